// Round 7
// baseline (10018.428 us; speedup 1.0000x reference)
//
#include <hip/hip_runtime.h>
#include <hip/hip_cooperative_groups.h>
#include <math.h>

namespace cg = cooperative_groups;

#define HDIM 1024
#define BROWS 256
#define TSTEPS 64
#define TH3 3072
#define RSCALE 1024.0f
#define RINV   0.0009765625f   // 2^-10

typedef _Float16 half8 __attribute__((ext_vector_type(8)));
typedef _Float16 half4v __attribute__((ext_vector_type(4)));
typedef _Float16 half2v __attribute__((ext_vector_type(2)));
typedef float float4v __attribute__((ext_vector_type(4)));

__device__ __forceinline__ float sigmoidf_(float x) {
    return 1.0f / (1.0f + __expf(-x));
}

// halfword index of (m,k) in a [256][1024] plane in MFMA A/B-fragment order:
// [mtile][ktile][lane][slot], lane=(m&15)+16*((k&31)>>3), slot=k&7.
__device__ __forceinline__ int frag_idx(int m, int k) {
    return (((m >> 4) * 32 + (k >> 5)) * 64 + ((m & 15) + (((k & 31) >> 3) << 4))) * 8 + (k & 7);
}

__device__ __forceinline__ void split16(float v, _Float16* hp, _Float16* lp) {
    const _Float16 h = (_Float16)v;
    *hp = h;
    *lp = (_Float16)((v - (float)h) * RSCALE);
}

// Split-fp16 3-pass MFMA over K=1024 with 2-deep register prefetch of global
// A-fragments; B-panel (this block's columns) from LDS.
__device__ __forceinline__ void mfma_panel(
    const half8* __restrict__ AH, const half8* __restrict__ AL,
    const _Float16* __restrict__ Wh, const _Float16* __restrict__ Wl,
    int mt0, int mt1, int lane,
    float4v& aH0, float4v& aX0, float4v& aH1, float4v& aX1)
{
    half8 c0h[2], c0l[2], c1h[2], c1l[2];
#pragma unroll
    for (int q = 0; q < 2; ++q) {
        c0h[q] = AH[(mt0 * 32 + q) * 64 + lane];
        c0l[q] = AL[(mt0 * 32 + q) * 64 + lane];
        c1h[q] = AH[(mt1 * 32 + q) * 64 + lane];
        c1l[q] = AL[(mt1 * 32 + q) * 64 + lane];
    }
#pragma unroll
    for (int kt = 0; kt < 32; ++kt) {
        const int cb = kt & 1;
        half8 n0h, n0l, n1h, n1l;
        if (kt < 30) {
            n0h = AH[(mt0 * 32 + kt + 2) * 64 + lane];
            n0l = AL[(mt0 * 32 + kt + 2) * 64 + lane];
            n1h = AH[(mt1 * 32 + kt + 2) * 64 + lane];
            n1l = AL[(mt1 * 32 + kt + 2) * 64 + lane];
        }
        const half8 bhv = *(const half8*)&Wh[kt * 512 + lane * 8];
        const half8 blv = *(const half8*)&Wl[kt * 512 + lane * 8];
        aH0 = __builtin_amdgcn_mfma_f32_16x16x32_f16(c0h[cb], bhv, aH0, 0, 0, 0);
        aX0 = __builtin_amdgcn_mfma_f32_16x16x32_f16(c0l[cb], bhv, aX0, 0, 0, 0);
        aX0 = __builtin_amdgcn_mfma_f32_16x16x32_f16(c0h[cb], blv, aX0, 0, 0, 0);
        aH1 = __builtin_amdgcn_mfma_f32_16x16x32_f16(c1h[cb], bhv, aH1, 0, 0, 0);
        aX1 = __builtin_amdgcn_mfma_f32_16x16x32_f16(c1l[cb], bhv, aX1, 0, 0, 0);
        aX1 = __builtin_amdgcn_mfma_f32_16x16x32_f16(c1h[cb], blv, aX1, 0, 0, 0);
        if (kt < 30) { c0h[cb] = n0h; c0l[cb] = n0l; c1h[cb] = n1h; c1l[cb] = n1l; }
    }
}

// ===========================================================================
// Persistent cooperative: 256 blocks x 512 threads (8 waves, 2/SIMD).
// LDS: WAh/WAl (16 cols of [W_out|W_r], B-frag order, split f16) 64 KB +
//      WBh/WBl (12 gate cols of W_k, n=jj*3+ch) 64 KB + 20 KB f32 scratch
//      (phase-A C transpose [8][2][16][20] / phase-B mx bounce [256][13]).
// Per step: phase A (MFMA, coalesced epilogue), sync, phase B (MFMA + all-
// thread fused gates; h slice lives in registers), sync.
// ===========================================================================
__global__ __launch_bounds__(512, 1) void decoder_mfma(
    const float* __restrict__ x,
    const float* __restrict__ W_fs, const float* __restrict__ b_fs,
    const float* __restrict__ W_out, const float* __restrict__ b_out,
    const float* __restrict__ W_k,  const float* __restrict__ W_r,
    const float* __restrict__ b_gru,
    float* __restrict__ dout,
    _Float16* __restrict__ hH, _Float16* __restrict__ hL,
    _Float16* __restrict__ oH, _Float16* __restrict__ oL,
    float* __restrict__ mh)
{
    extern __shared__ _Float16 ldsh[];
    _Float16* WAh = ldsh;              // 16384 halves each
    _Float16* WAl = ldsh + 16384;
    _Float16* WBh = ldsh + 32768;
    _Float16* WBl = ldsh + 49152;
    float*    scr = (float*)(ldsh + 65536);   // 5120 floats

    cg::grid_group grid = cg::this_grid();
    const int b    = blockIdx.x;
    const int tid  = threadIdx.x;
    const int wv   = tid >> 6;
    const int lane = tid & 63;
    const int nn   = lane & 15;
    const int kq   = lane >> 4;
    const int mt0  = 2 * wv, mt1 = 2 * wv + 1;

    // ---------- one-time: pack weight panels into LDS fragment order -------
    {
        const float* srcA; int ldwA, coffA;
        if (b < 64) { srcA = W_out; ldwA = HDIM; coffA = 16 * b; }
        else        { srcA = W_r;   ldwA = TH3;  coffA = 16 * b - 1024; }
        for (int idx = tid; idx < 16384; idx += 512) {
            const int k = idx >> 4, n = idx & 15;
            const float w = srcA[(size_t)k * ldwA + coffA + n];
            const int hw = ((k >> 5) * 64 + n + (((k & 31) >> 3) << 4)) * 8 + (k & 7);
            split16(w, &WAh[hw], &WAl[hw]);
        }
        for (int idx = tid; idx < 16384; idx += 512) {
            const int k = idx >> 4, n = idx & 15;
            float w = 0.0f;
            if (n < 12) {
                const int jj = n / 3, ch = n - 3 * jj;
                w = W_k[(size_t)k * TH3 + ch * 1024 + 4 * b + jj];
            }
            const int hw = ((k >> 5) * 64 + n + (((k & 31) >> 3) << 4)) * 8 + (k & 7);
            split16(w, &WBh[hw], &WBl[hw]);
        }
    }

    // ---------- biases ----------
    const int cA = 16 * b + nn;                       // phase-A concat col
    const float bA = (b < 64) ? b_out[cA] : b_gru[TH3 + cA - 1024];
    float bB = 0.0f;
    if (nn < 12) {
        const int jj = nn / 3, ch = nn - 3 * jj;
        bB = b_gru[ch * 1024 + 4 * b + jj];
    }

    // ---------- phase 0: h0 = tanh(x @ W_fs + b_fs); h slice -> registers --
    const int grow  = tid & 255;                      // gate-phase row
    const int ghalf = tid >> 8;
    const int gj0   = 4 * b + 2 * ghalf;              // this thread's 2 h-cols
    float hcur[2];
    {
        float a0 = 0.0f, a1 = 0.0f;
        const float* xr = x + (size_t)grow * HDIM;
        for (int k = 0; k < HDIM; k += 4) {
            const float4 xv = *(const float4*)(xr + k);
#pragma unroll
            for (int kk = 0; kk < 4; ++kk) {
                const float2 wv2 = *(const float2*)(W_fs + (size_t)(k + kk) * HDIM + gj0);
                const float av = (&xv.x)[kk];
                a0 = fmaf(av, wv2.x, a0);
                a1 = fmaf(av, wv2.y, a1);
            }
        }
        hcur[0] = tanhf(a0 + b_fs[gj0]);
        hcur[1] = tanhf(a1 + b_fs[gj0 + 1]);
        _Float16 h0h, h0l, h1h, h1l;
        split16(hcur[0], &h0h, &h0l);
        split16(hcur[1], &h1h, &h1l);
        const int fi = frag_idx(grow, gj0);           // gj0 even -> fi, fi+1 adjacent
        *(half2v*)&hH[fi] = half2v{h0h, h1h};
        *(half2v*)&hL[fi] = half2v{h0l, h1l};
    }
    grid.sync();

    // ---------- recurrence ----------
    for (int t = 0; ; ++t) {
        // ===== phase A: [out | mh] = h @ [W_out | W_r] =====
        {
            float4v aH0 = {0.f,0.f,0.f,0.f}, aX0 = {0.f,0.f,0.f,0.f};
            float4v aH1 = {0.f,0.f,0.f,0.f}, aX1 = {0.f,0.f,0.f,0.f};
            mfma_panel((const half8*)hH, (const half8*)hL, WAh, WAl,
                       mt0, mt1, lane, aH0, aX0, aH1, aX1);
            // write C tiles (bias+act applied) into per-wave LDS scratch
            float* Cs = scr + wv * 640;               // [2][16][20]
#pragma unroll
            for (int r = 0; r < 4; ++r) {
                float v0 = aH0[r] + aX0[r] * RINV + bA;
                float v1 = aH1[r] + aX1[r] * RINV + bA;
                if (b < 64) { v0 = fmaxf(v0, 0.0f); v1 = fmaxf(v1, 0.0f); }
                Cs[(kq * 4 + r) * 20 + nn]       = v0;
                Cs[320 + (kq * 4 + r) * 20 + nn] = v1;
            }
            __syncthreads();
            // coalesced read-back + stores: lane -> (row_local = lane>>2, 4 cols)
            const int rl  = lane >> 2;
            const int cq4 = (lane & 3) << 2;
            const float4v v0 = *(const float4v*)&Cs[rl * 20 + cq4];
            const float4v v1 = *(const float4v*)&Cs[320 + rl * 20 + cq4];
#pragma unroll
            for (int m = 0; m < 2; ++m) {
                const int row = (m == 0 ? mt0 : mt1) * 16 + rl;
                const float4v v = (m == 0) ? v0 : v1;
                if (b < 64) {
                    const int col = 16 * b + cq4;
                    if (t >= 1) {
                        float4v* dp = (float4v*)(dout + (size_t)row * (TSTEPS * HDIM)
                                                 + (size_t)(t - 1) * HDIM + col);
                        __builtin_nontemporal_store(v, dp);
                    }
                    if (t < TSTEPS) {
                        half4v vh, vl;
#pragma unroll
                        for (int i = 0; i < 4; ++i) {
                            _Float16 hh, ll;
                            split16(v[i], &hh, &ll);
                            vh[i] = hh; vl[i] = ll;
                        }
                        const int fi = frag_idx(row, col);
                        *(half4v*)&oH[fi] = vh;
                        *(half4v*)&oL[fi] = vl;
                    }
                } else if (t < TSTEPS) {
                    const int col = 16 * (b - 64) + cq4;
                    *(float4v*)(mh + (size_t)row * TH3 + col) = v;
                }
            }
        }
        if (t == TSTEPS) break;
        grid.sync();

        // ===== phase B: mx = out @ W_k + fused GRU gates -> h =====
        {
            // prefetch this thread's mh gate operands (written in phase A)
            const float2 mz = *(const float2*)&mh[(size_t)grow * TH3 + gj0];
            const float2 mr = *(const float2*)&mh[(size_t)grow * TH3 + 1024 + gj0];
            const float2 mv = *(const float2*)&mh[(size_t)grow * TH3 + 2048 + gj0];
            float4v aH0 = {0.f,0.f,0.f,0.f}, aX0 = {0.f,0.f,0.f,0.f};
            float4v aH1 = {0.f,0.f,0.f,0.f}, aX1 = {0.f,0.f,0.f,0.f};
            mfma_panel((const half8*)oH, (const half8*)oL, WBh, WBl,
                       mt0, mt1, lane, aH0, aX0, aH1, aX1);
            // bounce mx through LDS: [256][13]
            if (nn < 12) {
#pragma unroll
                for (int r = 0; r < 4; ++r) {
                    scr[(mt0 * 16 + kq * 4 + r) * 13 + nn] = aH0[r] + aX0[r] * RINV + bB;
                    scr[(mt1 * 16 + kq * 4 + r) * 13 + nn] = aH1[r] + aX1[r] * RINV + bB;
                }
            }
            __syncthreads();
            // all 512 threads: gates for (grow, gj0 + {0,1})
            _Float16 hh[2], hl[2];
#pragma unroll
            for (int q = 0; q < 2; ++q) {
                const int jj = 2 * ghalf + q;
                const float xz = scr[grow * 13 + jj * 3 + 0];
                const float xr = scr[grow * 13 + jj * 3 + 1];
                const float xh = scr[grow * 13 + jj * 3 + 2];
                const float z    = sigmoidf_(xz + ((q == 0) ? mz.x : mz.y));
                const float rg   = sigmoidf_(xr + ((q == 0) ? mr.x : mr.y));
                const float cand = tanhf(xh + rg * ((q == 0) ? mv.x : mv.y));
                const float hn = z * hcur[q] + (1.0f - z) * cand;
                hcur[q] = hn;
                split16(hn, &hh[q], &hl[q]);
            }
            const int fi = frag_idx(grow, gj0);
            *(half2v*)&hH[fi] = half2v{hh[0], hh[1]};
            *(half2v*)&hL[fi] = half2v{hl[0], hl[1]};
        }
        grid.sync();
    }
}

// ===========================================================================
// Fallback path (round-2 kernels) — used only if cooperative launch fails.
// ===========================================================================
__global__ __launch_bounds__(128) void gemmA(
    const float* __restrict__ A,
    const float* __restrict__ W0, const float* __restrict__ b0, int act0,
    float* __restrict__ C0, float* __restrict__ C2,
    const float* __restrict__ W1, const float* __restrict__ b1,
    float* __restrict__ C1)
{
    __shared__ __align__(16) float Ass[32][36];
    __shared__ __align__(16) float Ws[32][68];
    const int tid = threadIdx.x;
    const int bx = blockIdx.x, by = blockIdx.y;
    const int r0 = by * 32;
    const bool reg0 = (bx < 16);
    const int c0 = reg0 ? bx * 64 : (bx - 16) * 64;
    const float* __restrict__ W = reg0 ? W0 : W1;
    const int ldw = reg0 ? 1024 : 3072;
    const int arow = tid >> 2;
    const int ak   = (tid & 3) << 2;
    const int wrow = tid >> 4;
    const int wcol = (tid & 15) << 2;
    const int ty = tid >> 4;
    const int tx = tid & 15;
    float acc[4][4] = {};
    const float* Ap = A + (size_t)(r0 + arow) * 1024 + ak;
    const float* Wp = W + (size_t)wrow * ldw + c0 + wcol;
    for (int k0 = 0; k0 < 1024; k0 += 32) {
        const float4 a0 = *(const float4*)(Ap + k0);
        const float4 a1 = *(const float4*)(Ap + k0 + 16);
        const float4 w0 = *(const float4*)(Wp + (size_t)k0 * ldw);
        const float4 w1 = *(const float4*)(Wp + (size_t)(k0 + 8) * ldw);
        const float4 w2 = *(const float4*)(Wp + (size_t)(k0 + 16) * ldw);
        const float4 w3 = *(const float4*)(Wp + (size_t)(k0 + 24) * ldw);
        __syncthreads();
        Ass[ak + 0][arow] = a0.x; Ass[ak + 1][arow] = a0.y;
        Ass[ak + 2][arow] = a0.z; Ass[ak + 3][arow] = a0.w;
        Ass[ak + 16][arow] = a1.x; Ass[ak + 17][arow] = a1.y;
        Ass[ak + 18][arow] = a1.z; Ass[ak + 19][arow] = a1.w;
        *(float4*)&Ws[wrow][wcol]      = w0;
        *(float4*)&Ws[wrow + 8][wcol]  = w1;
        *(float4*)&Ws[wrow + 16][wcol] = w2;
        *(float4*)&Ws[wrow + 24][wcol] = w3;
        __syncthreads();
#pragma unroll
        for (int kk = 0; kk < 32; ++kk) {
            const float4 a4 = *(const float4*)&Ass[kk][ty << 2];
            const float4 w4 = *(const float4*)&Ws[kk][tx << 2];
            const float a[4] = {a4.x, a4.y, a4.z, a4.w};
            const float w[4] = {w4.x, w4.y, w4.z, w4.w};
#pragma unroll
            for (int i = 0; i < 4; ++i)
#pragma unroll
                for (int j = 0; j < 4; ++j)
                    acc[i][j] = fmaf(a[i], w[j], acc[i][j]);
        }
    }
    const float* bias = reg0 ? b0 : b1;
    const float4 bv = *(const float4*)(bias + c0 + (tx << 2));
    const float bb[4] = {bv.x, bv.y, bv.z, bv.w};
#pragma unroll
    for (int i = 0; i < 4; ++i) {
        const int row = r0 + (ty << 2) + i;
        float v[4];
#pragma unroll
        for (int j = 0; j < 4; ++j) {
            float tv = acc[i][j] + bb[j];
            if (reg0) { tv = (act0 == 1) ? fmaxf(tv, 0.0f) : tanhf(tv); }
            v[j] = tv;
        }
        const float4 o = make_float4(v[0], v[1], v[2], v[3]);
        if (reg0) {
            *(float4*)(C0 + (size_t)row * 1024 + c0 + (tx << 2)) = o;
            if (C2)
                *(float4*)(C2 + (size_t)row * (TSTEPS * HDIM) + c0 + (tx << 2)) = o;
        } else {
            *(float4*)(C1 + (size_t)row * TH3 + c0 + (tx << 2)) = o;
        }
    }
}

__global__ __launch_bounds__(128) void gemmB(
    const float* __restrict__ A,
    const float* __restrict__ Wk,
    const float* __restrict__ bg,
    const float* __restrict__ mh,
    float* __restrict__ h)
{
    __shared__ __align__(16) float Ass[32][36];
    __shared__ __align__(16) float Ws[3][32][20];
    const int tid = threadIdx.x;
    const int j0 = blockIdx.x * 16;
    const int r0 = blockIdx.y * 32;
    const int arow = tid >> 2;
    const int ak   = (tid & 3) << 2;
    const int wr   = tid >> 2;
    const int wc   = (tid & 3) << 2;
    const int ty = tid >> 4;
    const int tx = tid & 15;
    float acc[3][4] = {};
    const float* Ap = A + (size_t)(r0 + arow) * 1024 + ak;
    const float* Wp = Wk + (size_t)wr * TH3 + j0 + wc;
    for (int k0 = 0; k0 < 1024; k0 += 32) {
        const float4 a0 = *(const float4*)(Ap + k0);
        const float4 a1 = *(const float4*)(Ap + k0 + 16);
        float4 wv[3];
#pragma unroll
        for (int c = 0; c < 3; ++c)
            wv[c] = *(const float4*)(Wp + (size_t)k0 * TH3 + c * 1024);
        __syncthreads();
        Ass[ak + 0][arow] = a0.x; Ass[ak + 1][arow] = a0.y;
        Ass[ak + 2][arow] = a0.z; Ass[ak + 3][arow] = a0.w;
        Ass[ak + 16][arow] = a1.x; Ass[ak + 17][arow] = a1.y;
        Ass[ak + 18][arow] = a1.z; Ass[ak + 19][arow] = a1.w;
#pragma unroll
        for (int c = 0; c < 3; ++c)
            *(float4*)&Ws[c][wr][wc] = wv[c];
        __syncthreads();
#pragma unroll
        for (int kk = 0; kk < 32; ++kk) {
            const float4 a4 = *(const float4*)&Ass[kk][ty << 2];
            const float a[4] = {a4.x, a4.y, a4.z, a4.w};
            const float wz = Ws[0][kk][tx];
            const float wr_ = Ws[1][kk][tx];
            const float wh = Ws[2][kk][tx];
#pragma unroll
            for (int i = 0; i < 4; ++i) {
                acc[0][i] = fmaf(a[i], wz, acc[0][i]);
                acc[1][i] = fmaf(a[i], wr_, acc[1][i]);
                acc[2][i] = fmaf(a[i], wh, acc[2][i]);
            }
        }
    }
    const int j = j0 + tx;
    const float bz = bg[j];
    const float br = bg[HDIM + j];
    const float bh = bg[2 * HDIM + j];
#pragma unroll
    for (int i = 0; i < 4; ++i) {
        const int row = r0 + (ty << 2) + i;
        const float* mhp = mh + (size_t)row * TH3;
        const float z  = sigmoidf_(acc[0][i] + bz + mhp[j]);
        const float rg = sigmoidf_(acc[1][i] + br + mhp[HDIM + j]);
        const float cand = tanhf(acc[2][i] + bh + rg * mhp[2 * HDIM + j]);
        const size_t hi = (size_t)row * HDIM + j;
        const float ho = h[hi];
        h[hi] = z * ho + (1.0f - z) * cand;
    }
}

extern "C" void kernel_launch(void* const* d_in, const int* in_sizes, int n_in,
                              void* d_out, int out_size, void* d_ws, size_t ws_size,
                              hipStream_t stream) {
    const float* x     = (const float*)d_in[0];
    const float* W_fs  = (const float*)d_in[1];
    const float* b_fs  = (const float*)d_in[2];
    const float* W_out = (const float*)d_in[3];
    const float* b_out = (const float*)d_in[4];
    const float* W_k   = (const float*)d_in[5];
    const float* W_r   = (const float*)d_in[6];
    const float* b_gru = (const float*)d_in[7];
    float* out = (float*)d_out;            // [B, T, H]

    char* ws = (char*)d_ws;
    _Float16* hH = (_Float16*)(ws);
    _Float16* hL = (_Float16*)(ws + 512 * 1024);
    _Float16* oH = (_Float16*)(ws + 1024 * 1024);
    _Float16* oL = (_Float16*)(ws + 1536 * 1024);
    float*    mh = (float*)   (ws + 2048 * 1024);

    void* args[] = {
        (void*)&x, (void*)&W_fs, (void*)&b_fs, (void*)&W_out, (void*)&b_out,
        (void*)&W_k, (void*)&W_r, (void*)&b_gru, (void*)&out,
        (void*)&hH, (void*)&hL, (void*)&oH, (void*)&oL, (void*)&mh
    };
    // 128 KB weights + 20 KB f32 scratch = 151552 B dynamic LDS
    const size_t lds_bytes = 65536 * sizeof(_Float16) + 5120 * sizeof(float);
    hipError_t err = hipLaunchCooperativeKernel(
        (const void*)decoder_mfma, dim3(256), dim3(512),
        args, lds_bytes, stream);

    if (err != hipSuccess) {
        // fallback: round-2 multi-launch fp32 path
        float* h    = (float*)d_ws;
        float* outb = h    + BROWS * HDIM;
        float* mhf  = outb + BROWS * HDIM;
        const dim3 blk(128);
        const dim3 gridInit(16, 8);
        const dim3 gridA(64, 8);
        const dim3 gridB(64, 8);
        gemmA<<<gridInit, blk, 0, stream>>>(x, W_fs, b_fs, 2, h, nullptr,
                                            nullptr, nullptr, nullptr);
        for (int t = 0; t < TSTEPS; ++t) {
            float* c2 = (t >= 1) ? (out + (size_t)(t - 1) * HDIM) : nullptr;
            gemmA<<<gridA, blk, 0, stream>>>(h, W_out, b_out, 1, outb, c2,
                                             W_r, b_gru + TH3, mhf);
            gemmB<<<gridB, blk, 0, stream>>>(outb, W_k, b_gru, mhf, h);
        }
        gemmA<<<gridInit, blk, 0, stream>>>(h, W_out, b_out, 1, outb,
                                            out + (size_t)(TSTEPS - 1) * HDIM,
                                            nullptr, nullptr, nullptr);
    }
}